// Round 9
// baseline (741.465 us; speedup 1.0000x reference)
//
#include <hip/hip_runtime.h>

typedef unsigned short u16;
typedef __attribute__((ext_vector_type(8))) short short8;
typedef __attribute__((ext_vector_type(4))) float float4v;

#define HID 64
#define MOLD 9
#define BSH 10           // bucket covers 1<<BSH = 1024 nodes
#define NBM 256          // max buckets (N <= 262144; src packs in 18 bits)
#define NBLK 256         // partition blocks

__device__ __forceinline__ float bf2f(u16 u) {
    return __uint_as_float(((unsigned)u) << 16);
}
__device__ __forceinline__ u16 f2bf(float f) {
    unsigned x = __float_as_uint(f);
    unsigned r = (x + 0x7FFFu + ((x >> 16) & 1u)) >> 16;  // round-nearest-even
    return (u16)r;
}
__device__ __forceinline__ void unpack_add(uint4 r, float* a) {
    a[0] += __uint_as_float(r.x << 16); a[1] += __uint_as_float(r.x & 0xffff0000u);
    a[2] += __uint_as_float(r.y << 16); a[3] += __uint_as_float(r.y & 0xffff0000u);
    a[4] += __uint_as_float(r.z << 16); a[5] += __uint_as_float(r.z & 0xffff0000u);
    a[6] += __uint_as_float(r.w << 16); a[7] += __uint_as_float(r.w & 0xffff0000u);
}
__device__ __forceinline__ void unpack_set(uint4 r, float* a) {
    a[0] = __uint_as_float(r.x << 16); a[1] = __uint_as_float(r.x & 0xffff0000u);
    a[2] = __uint_as_float(r.y << 16); a[3] = __uint_as_float(r.y & 0xffff0000u);
    a[4] = __uint_as_float(r.z << 16); a[5] = __uint_as_float(r.z & 0xffff0000u);
    a[6] = __uint_as_float(r.w << 16); a[7] = __uint_as_float(r.w & 0xffff0000u);
}

// ---- dtype probe ----
__global__ void k_detect(const u16* __restrict__ p, int n, int* __restrict__ flag) {
    bool bad = false;
    for (int i = threadIdx.x; i < n; i += 256) {
        float v = bf2f(p[i]);
        if (!(v == v) || fabsf(v) > 1000.f) bad = true;
    }
    if (bad) atomicOr(flag, 1);
}

// ---- stage all weights as bf16 (multi-block, flat index -> segment) ----
__global__ void k_cvt_w(const void* W1, const void* b1, const void* W2, const void* b2,
                        const void* W3, const void* b3, const void* Wl, const void* bl,
                        const int* __restrict__ flag, u16* __restrict__ wbf) {
    int mode = *flag;
    int i = blockIdx.x * 256 + threadIdx.x;
    if (i >= 17216) return;
    const void* s; int base;
    if (i < 576)        { s = W1; base = 0; }
    else if (i < 640)   { s = b1; base = 576; }
    else if (i < 4736)  { s = W2; base = 640; }
    else if (i < 4800)  { s = b2; base = 4736; }
    else if (i < 8896)  { s = W3; base = 4800; }
    else if (i < 8960)  { s = b3; base = 8896; }
    else if (i < 17152) { s = Wl; base = 8960; }
    else                { s = bl; base = 17152; }
    int o = i - base;
    wbf[i] = mode ? f2bf(((const float*)s)[o]) : ((const u16*)s)[o];
}

// ==== atomic-free two-level radix CSR build ====
__global__ __launch_bounds__(256) void k_hist(const int* __restrict__ ei, int E, int nb,
                                              int chunk, int* __restrict__ cntmat) {
    __shared__ int h[NBM];
    int tid = threadIdx.x, k = blockIdx.x;
    for (int i = tid; i < nb; i += 256) h[i] = 0;
    __syncthreads();
    int e0 = k * chunk, e1 = e0 + chunk; if (e1 > E) e1 = E;
    for (int e = e0 + tid; e < e1; e += 256)
        atomicAdd(&h[ei[E + e] >> BSH], 1);
    __syncthreads();
    for (int b = tid; b < nb; b += 256) cntmat[b * NBLK + k] = h[b];
}

__global__ __launch_bounds__(1024) void k_scanmat(int* __restrict__ cntmat, int total) {
    __shared__ int ps[1024];
    int tid = threadIdx.x;
    int chunk = (total + 1023) >> 10;
    int i0 = tid * chunk, i1 = i0 + chunk; if (i1 > total) i1 = total;
    int sum = 0;
    for (int i = i0; i < i1; i++) sum += cntmat[i];
    ps[tid] = sum;
    __syncthreads();
    for (int off = 1; off < 1024; off <<= 1) {
        int t = (tid >= off) ? ps[tid - off] : 0;
        __syncthreads();
        ps[tid] += t;
        __syncthreads();
    }
    int run = ps[tid] - sum;
    for (int i = i0; i < i1; i++) { int c = cntmat[i]; cntmat[i] = run; run += c; }
}

__global__ __launch_bounds__(256) void k_scatter(const int* __restrict__ ei, int E, int nb,
                                                 int chunk, const int* __restrict__ offmat,
                                                 unsigned* __restrict__ staging) {
    __shared__ int cur[NBM];
    int tid = threadIdx.x, k = blockIdx.x;
    for (int b = tid; b < nb; b += 256) cur[b] = offmat[b * NBLK + k];
    __syncthreads();
    int e0 = k * chunk, e1 = e0 + chunk; if (e1 > E) e1 = E;
    for (int e = e0 + tid; e < e1; e += 256) {
        int s = ei[e];
        int d = ei[E + e];
        int b = d >> BSH;
        int p = atomicAdd(&cur[b], 1);
        staging[p] = (unsigned)s | ((unsigned)(d & ((1 << BSH) - 1)) << 18);
    }
}

__global__ __launch_bounds__(256) void k_p4(const unsigned* __restrict__ staging,
                                            const int* __restrict__ offmat, int nb, int N, int E,
                                            int* __restrict__ col, int* __restrict__ rowptr,
                                            float* __restrict__ dinv) {
    __shared__ int cnt[1 << BSH];
    __shared__ int cur[1 << BSH];
    __shared__ int ps[256];
    int b = blockIdx.x, tid = threadIdx.x;
    int s0 = offmat[b * NBLK];
    int s1 = (b == nb - 1) ? E : offmat[(b + 1) * NBLK];
    for (int i = tid; i < (1 << BSH); i += 256) cnt[i] = 0;
    __syncthreads();
    for (int i = s0 + tid; i < s1; i += 256)
        atomicAdd(&cnt[staging[i] >> 18], 1);
    __syncthreads();
    int base4 = tid * 4;
    int c0 = cnt[base4], c1 = cnt[base4 + 1], c2 = cnt[base4 + 2], c3 = cnt[base4 + 3];
    int tsum = c0 + c1 + c2 + c3;
    ps[tid] = tsum;
    __syncthreads();
    for (int off = 1; off < 256; off <<= 1) {
        int t = (tid >= off) ? ps[tid - off] : 0;
        __syncthreads();
        ps[tid] += t;
        __syncthreads();
    }
    int ex = ps[tid] - tsum;
    int o0 = s0 + ex, o1 = o0 + c0, o2 = o1 + c1, o3 = o2 + c2;
    cur[base4] = o0; cur[base4 + 1] = o1; cur[base4 + 2] = o2; cur[base4 + 3] = o3;
    int v = (b << BSH) + base4;
    if (v < N)     { rowptr[v] = o0;     dinv[v] = rsqrtf((float)(c0 + 1)); }
    if (v + 1 < N) { rowptr[v + 1] = o1; dinv[v + 1] = rsqrtf((float)(c1 + 1)); }
    if (v + 2 < N) { rowptr[v + 2] = o2; dinv[v + 2] = rsqrtf((float)(c2 + 1)); }
    if (v + 3 < N) { rowptr[v + 3] = o3; dinv[v + 3] = rsqrtf((float)(c3 + 1)); }
    if (b == nb - 1 && tid == 0) rowptr[N] = E;
    __syncthreads();
    for (int i = s0 + tid; i < s1; i += 256) {
        unsigned w = staging[i];
        int p = atomicAdd(&cur[w >> 18], 1);
        col[p] = (int)(w & 0x3FFFF);
    }
}

// ---- layer-1 dense (reads x directly, mode branch; y = dinv * (x@W1)) ----
__global__ void k_l1(const void* __restrict__ x, const u16* __restrict__ wseg,
                     const float* __restrict__ dinv, const int* __restrict__ flag,
                     int N, u16* __restrict__ y) {
    __shared__ float w[MOLD * HID];
    int tid = threadIdx.x;
    int mode = *flag;
    for (int i = tid; i < MOLD * HID; i += blockDim.x) w[i] = bf2f(wseg[i]);
    __syncthreads();
    int v = blockIdx.x * 4 + (tid >> 6);
    int f = tid & 63;
    if (v >= N) return;
    float acc = 0.f;
#pragma unroll
    for (int k = 0; k < MOLD; k++) {
        float xv = mode ? ((const float*)x)[v * MOLD + k]
                        : bf2f(((const u16*)x)[v * MOLD + k]);
        acc += xv * w[k * HID + f];
    }
    y[v * HID + f] = f2bf(dinv[v] * acc);
}

// ---- gather core: raw aggregated value (self + neighbors), halving reduction ----
// Returns feature idx = fg*8 + bitrev3(eslot) of (y[v] + sum_{u->v} y[u]).
__device__ __forceinline__ float gather_node_raw(const u16* __restrict__ y,
                                                 const int* __restrict__ rowptr,
                                                 const int* __restrict__ col,
                                                 int v, int eslot, int fg) {
    float acc[8];
    const u16* yf = y + fg * 8;   // lane-constant feature offset
    if (eslot == 0) {
        unpack_set(*(const uint4*)(yf + (size_t)v * HID), acc);
    } else {
#pragma unroll
        for (int j = 0; j < 8; j++) acc[j] = 0.f;
    }
    int e = rowptr[v + 1];
    for (int i = rowptr[v] + eslot; i < e; i += 8) {
        int u = col[i];
        uint4 r = *(const uint4*)(yf + (size_t)u * HID);
        unpack_add(r, acc);
    }
    // halving butterfly over eslot bits (lane bits 3,4,5): 8+4+2 = 14 shfl
    bool e0 = (eslot & 1) != 0, e1 = (eslot & 2) != 0, e2 = (eslot & 4) != 0;
    float s[8];
#pragma unroll
    for (int j = 0; j < 8; j++) s[j] = acc[j] + __shfl_xor(acc[j], 8);
    float b4[4];
#pragma unroll
    for (int k = 0; k < 4; k++) b4[k] = e0 ? s[k + 4] : s[k];
#pragma unroll
    for (int k = 0; k < 4; k++) b4[k] += __shfl_xor(b4[k], 16);
    float c2[2];
    c2[0] = e1 ? b4[2] : b4[0];
    c2[1] = e1 ? b4[3] : b4[1];
    c2[0] += __shfl_xor(c2[0], 32);
    c2[1] += __shfl_xor(c2[1], 32);
    return e2 ? c2[1] : c2[0];
}

// ---- agg layer 1: z1' = dinv * relu(dinv*A + b1) ----
__global__ __launch_bounds__(256, 4) void k_agg(
        const u16* __restrict__ y, const int* __restrict__ rowptr,
        const int* __restrict__ col, const float* __restrict__ dinv,
        const u16* __restrict__ bseg, int N, u16* __restrict__ h) {
    int lane = threadIdx.x & 63;
    int eslot = lane >> 3, fg = lane & 7;
    int idx = fg * 8 + ((eslot & 1) << 2) + (eslot & 2) + ((eslot >> 2) & 1);
    float bias = bf2f(bseg[idx]);
    int wid = (blockIdx.x * blockDim.x + threadIdx.x) >> 6;
    int nw = (gridDim.x * blockDim.x) >> 6;
    for (int v = wid; v < N; v += nw) {
        float dv = dinv[v];
        float val = gather_node_raw(y, rowptr, col, v, eslot, fg);
        float hv = fmaxf(dv * val + bias, 0.f);
        h[(size_t)v * HID + idx] = f2bf(dv * hv);      // dinv baked for next gather
    }
}

// ---- agg layer 2 fused with W2: z2' = dinv * relu(dinv*(A@W2) + b2) ----
// Per-wave LDS A-tile of 16 nodes; MFMA 16x16x32 vs LDS-transposed W (pad to 72).
__global__ __launch_bounds__(256, 4) void k_aggmm(
        const u16* __restrict__ y, const int* __restrict__ rowptr,
        const int* __restrict__ col, const float* __restrict__ dinv,
        const u16* __restrict__ W, const u16* __restrict__ bseg,
        int N, u16* __restrict__ z) {
    __shared__ u16 wt[HID][72];      // W transposed: wt[colf][k], pad 72 kills conflicts
    __shared__ u16 at[4][16][72];    // per-wave A tiles (node-local row, feat)
    int tid = threadIdx.x;
    for (int i = tid; i < HID * HID; i += 256) {
        int k = i >> 6, c = i & 63;
        wt[c][k] = W[i];
    }
    __syncthreads();
    int lane = tid & 63;
    int wv = tid >> 6;
    int eslot = lane >> 3, fg = lane & 7;
    int idx = fg * 8 + ((eslot & 1) << 2) + (eslot & 2) + ((eslot >> 2) & 1);
    int q = lane >> 4, m = lane & 15;
    float bb[4];
#pragma unroll
    for (int t = 0; t < 4; t++) bb[t] = bf2f(bseg[t * 16 + m]);
    int gwid = (blockIdx.x * blockDim.x + tid) >> 6;
    int nw = (gridDim.x * blockDim.x) >> 6;
    int ngroups = (N + 15) >> 4;
    for (int g = gwid; g < ngroups; g += nw) {
        int v0 = g << 4;
        int vend = N - v0; if (vend > 16) vend = 16;
        for (int vl = 0; vl < vend; ++vl) {
            float val = gather_node_raw(y, rowptr, col, v0 + vl, eslot, fg);
            at[wv][vl][idx] = f2bf(val);             // same-wave ds: no barrier needed
        }
        short8 a0 = *(const short8*)&at[wv][m][q * 8];
        short8 a1 = *(const short8*)&at[wv][m][32 + q * 8];
        float4v c4[4];
#pragma unroll
        for (int t = 0; t < 4; t++) {
            float4v cz = {0.f, 0.f, 0.f, 0.f};
            short8 b0 = *(const short8*)&wt[t * 16 + m][q * 8];
            cz = __builtin_amdgcn_mfma_f32_16x16x32_bf16(a0, b0, cz, 0, 0, 0);
            short8 b1 = *(const short8*)&wt[t * 16 + m][32 + q * 8];
            cz = __builtin_amdgcn_mfma_f32_16x16x32_bf16(a1, b1, cz, 0, 0, 0);
            c4[t] = cz;
        }
        // C layout: node = v0 + q*4 + r, feat = t*16 + m
#pragma unroll
        for (int r = 0; r < 4; r++) {
            int node = v0 + q * 4 + r;
            if (node < N) {
                float dv = dinv[node];
#pragma unroll
                for (int t = 0; t < 4; t++) {
                    float h = fmaxf(dv * c4[t][r] + bb[t], 0.f);
                    z[(size_t)node * HID + t * 16 + m] = f2bf(dv * h);
                }
            }
        }
    }
}

// ---- agg layer 3 + fused pooling (unchanged from round 8) ----
__global__ __launch_bounds__(256, 4) void k_aggpool(
        const u16* __restrict__ y, const int* __restrict__ rowptr,
        const int* __restrict__ col, const float* __restrict__ dinv,
        const u16* __restrict__ bseg, const int* __restrict__ batch, int N,
        float* __restrict__ hsum, int* __restrict__ hmax, int* __restrict__ cnt) {
    int lane = threadIdx.x & 63;
    int eslot = lane >> 3, fg = lane & 7;
    int idx = fg * 8 + ((eslot & 1) << 2) + (eslot & 2) + ((eslot >> 2) & 1);
    float bias = bf2f(bseg[idx]);
    int wid = (blockIdx.x * blockDim.x + threadIdx.x) >> 6;
    int nw = (gridDim.x * blockDim.x) >> 6;
    int cpw = (N + nw - 1) / nw;
    int v0 = wid * cpw;
    int v1 = v0 + cpw; if (v1 > N) v1 = N;
    int gcur = -1, pcnt = 0;
    float psum = 0.f, pmax = 0.f;
    for (int v = v0; v < v1; ++v) {
        float val = gather_node_raw(y, rowptr, col, v, eslot, fg);
        float hv = fmaxf(dinv[v] * val + bias, 0.f);
        int g = batch[v];
        if (g != gcur) {
            if (gcur >= 0) {
                atomicAdd(&hsum[gcur * HID + idx], psum);
                atomicMax(&hmax[gcur * HID + idx], __float_as_int(pmax));
                if (lane == 0) atomicAdd(&cnt[gcur], pcnt);
            }
            psum = 0.f; pmax = 0.f; pcnt = 0;
            gcur = g;
        }
        pcnt++;
        psum += hv;
        pmax = fmaxf(pmax, hv);
    }
    if (gcur >= 0) {
        atomicAdd(&hsum[gcur * HID + idx], psum);
        atomicMax(&hmax[gcur * HID + idx], __float_as_int(pmax));
        if (lane == 0) atomicAdd(&cnt[gcur], pcnt);
    }
}

// ---- MFMA 64x64 dense, NO dinv (input already dinv-baked): y = h@W ----
__global__ __launch_bounds__(256, 4) void k_mm(
        const u16* __restrict__ h, const u16* __restrict__ W,
        int N, u16* __restrict__ y) {
    int lane = threadIdx.x & 63;
    int q = lane >> 4, m = lane & 15;
    int wid = (blockIdx.x * blockDim.x + threadIdx.x) >> 6;
    int nw = (gridDim.x * blockDim.x) >> 6;
    short8 bfrag[4][2];
#pragma unroll
    for (int t = 0; t < 4; ++t)
#pragma unroll
        for (int kh = 0; kh < 2; ++kh) {
            short8 bv;
#pragma unroll
            for (int j = 0; j < 8; ++j)
                bv[j] = (short)W[(kh * 32 + q * 8 + j) * HID + t * 16 + m];
            bfrag[t][kh] = bv;
        }
    const float4v zero = {0.f, 0.f, 0.f, 0.f};
    int ntiles = (N + 15) >> 4;
    for (int tile = wid; tile < ntiles; tile += nw) {
        int base = tile * 16;
        int row = base + m;
        short8 a0 = {0, 0, 0, 0, 0, 0, 0, 0}, a1 = a0;
        if (row < N) {
            uint4 r0 = *(const uint4*)(h + (size_t)row * HID + q * 8);
            uint4 r1 = *(const uint4*)(h + (size_t)row * HID + 32 + q * 8);
            a0 = __builtin_bit_cast(short8, r0);
            a1 = __builtin_bit_cast(short8, r1);
        }
        float4v c[4];
#pragma unroll
        for (int t = 0; t < 4; ++t) c[t] = zero;
#pragma unroll
        for (int t = 0; t < 4; ++t) {
            c[t] = __builtin_amdgcn_mfma_f32_16x16x32_bf16(a0, bfrag[t][0], c[t], 0, 0, 0);
            c[t] = __builtin_amdgcn_mfma_f32_16x16x32_bf16(a1, bfrag[t][1], c[t], 0, 0, 0);
        }
#pragma unroll
        for (int r = 0; r < 4; ++r) {
            int node = base + q * 4 + r;
            if (node < N) {
#pragma unroll
                for (int t = 0; t < 4; ++t)
                    y[(size_t)node * HID + t * 16 + m] = f2bf(c[t][r]);
            }
        }
    }
}

// ---- final linear ----
__global__ void k_final(const float* __restrict__ hsum, const int* __restrict__ hmaxi,
                        const int* __restrict__ cnt, const u16* __restrict__ wlseg,
                        const u16* __restrict__ blseg, const int* __restrict__ flag,
                        int G, void* __restrict__ out) {
    __shared__ float w[2 * HID * HID];
    int tid = threadIdx.x;
    for (int i = tid; i < 2 * HID * HID; i += blockDim.x) w[i] = bf2f(wlseg[i]);
    __syncthreads();
    int g = blockIdx.x * 4 + (tid >> 6);
    int f = tid & 63;
    if (g >= G) return;
    float inv = 1.f / fmaxf((float)cnt[g], 1.f);
    float acc = bf2f(blseg[f]);
#pragma unroll 8
    for (int k = 0; k < HID; k++) acc += (hsum[g * HID + k] * inv) * w[k * HID + f];
#pragma unroll 8
    for (int k = 0; k < HID; k++) acc += __int_as_float(hmaxi[g * HID + k]) * w[(HID + k) * HID + f];
    int mode = *flag;
    if (mode) ((float*)out)[g * HID + f] = acc;
    else      ((u16*)out)[g * HID + f] = f2bf(acc);
}

extern "C" void kernel_launch(void* const* d_in, const int* in_sizes, int n_in,
                              void* d_out, int out_size, void* d_ws, size_t ws_size,
                              hipStream_t stream) {
    const void* x  = d_in[0];
    const int*  ei = (const int*)d_in[1];
    const int*  batch = (const int*)d_in[3];

    const int NX = in_sizes[0];
    const int N  = NX / MOLD;
    const int E  = in_sizes[1] / 2;
    const int G  = out_size / HID;
    const int nb = (N + (1 << BSH) - 1) >> BSH;

    char* p = (char*)d_ws;
    auto alloc = [&](size_t bytes) -> char* {
        char* r = p;
        p += (bytes + 255) & ~(size_t)255;
        return r;
    };
    int*   flag    = (int*)alloc(256);
    int*   rowptr  = (int*)alloc((size_t)(N + 1) * 4);
    float* dinv    = (float*)alloc((size_t)N * 4);
    int*   cntmat  = (int*)alloc((size_t)nb * NBLK * 4);
    u16*   wbf     = (u16*)alloc((size_t)17216 * 2);
    int*   colb    = (int*)alloc((size_t)E * 4);
    // hbuf region reused: staging (CSR build) -> hbf
    size_t hb = (size_t)N * HID * 2;
    size_t sb = (size_t)E * 4;
    size_t ub = hb > sb ? hb : sb;
    char* hbuf = alloc(ub);
    unsigned* staging = (unsigned*)hbuf;
    u16*      hbf     = (u16*)hbuf;
    u16*   ybf  = (u16*)alloc((size_t)N * HID * 2);
    float* hsum = (float*)alloc((size_t)G * HID * 4);
    int*   hmax = (int*)alloc((size_t)G * HID * 4);
    int*   cnt  = (int*)alloc((size_t)G * 4);

    hipMemsetAsync(flag, 0, 256, stream);
    hipMemsetAsync(hsum, 0, (size_t)G * HID * 4, stream);
    hipMemsetAsync(hmax, 0, (size_t)G * HID * 4, stream);
    hipMemsetAsync(cnt, 0, (size_t)G * 4, stream);

    k_detect<<<1, 256, 0, stream>>>((const u16*)x, 8192, flag);
    k_cvt_w<<<68, 256, 0, stream>>>(d_in[4], d_in[5], d_in[6], d_in[7],
                                    d_in[8], d_in[9], d_in[10], d_in[11], flag, wbf);

    int chunk = (E + NBLK - 1) / NBLK;
    k_hist<<<NBLK, 256, 0, stream>>>(ei, E, nb, chunk, cntmat);
    k_scanmat<<<1, 1024, 0, stream>>>(cntmat, nb * NBLK);
    k_scatter<<<NBLK, 256, 0, stream>>>(ei, E, nb, chunk, cntmat, staging);
    k_p4<<<nb, 256, 0, stream>>>(staging, cntmat, nb, N, E, colb, rowptr, dinv);

    // l1 writes ybf (y1 = dinv * x@W1); staging (aliasing hbf) dead after p4
    k_l1<<<(N + 3) / 4, 256, 0, stream>>>(x, wbf + 0, dinv, flag, N, ybf);

    k_agg<<<2048, 256, 0, stream>>>(ybf, rowptr, colb, dinv, wbf + 576, N, hbf);     // z1'
    k_aggmm<<<2048, 256, 0, stream>>>(hbf, rowptr, colb, dinv, wbf + 640, wbf + 4736,
                                      N, ybf);                                        // z2'
    k_mm<<<1024, 256, 0, stream>>>(ybf, wbf + 4800, N, hbf);                          // y3
    k_aggpool<<<2048, 256, 0, stream>>>(hbf, rowptr, colb, dinv, wbf + 8896, batch, N,
                                        hsum, hmax, cnt);

    k_final<<<(G + 3) / 4, 256, 0, stream>>>(hsum, hmax, cnt, wbf + 8960, wbf + 17152,
                                             flag, G, d_out);
}

// Round 10
// 592.098 us; speedup vs baseline: 1.2523x; 1.2523x over previous
//
#include <hip/hip_runtime.h>

typedef unsigned short u16;
typedef __attribute__((ext_vector_type(8))) short short8;
typedef __attribute__((ext_vector_type(4))) float float4v;

#define HID 64
#define MOLD 9
#define BSH 10           // bucket covers 1<<BSH = 1024 nodes
#define NBM 256          // max buckets (N <= 262144; src packs in 18 bits)
#define NBLK 256         // partition blocks

__device__ __forceinline__ float bf2f(u16 u) {
    return __uint_as_float(((unsigned)u) << 16);
}
__device__ __forceinline__ u16 f2bf(float f) {
    unsigned x = __float_as_uint(f);
    unsigned r = (x + 0x7FFFu + ((x >> 16) & 1u)) >> 16;  // round-nearest-even
    return (u16)r;
}
__device__ __forceinline__ void unpack_add(uint4 r, float* a) {
    a[0] += __uint_as_float(r.x << 16); a[1] += __uint_as_float(r.x & 0xffff0000u);
    a[2] += __uint_as_float(r.y << 16); a[3] += __uint_as_float(r.y & 0xffff0000u);
    a[4] += __uint_as_float(r.z << 16); a[5] += __uint_as_float(r.z & 0xffff0000u);
    a[6] += __uint_as_float(r.w << 16); a[7] += __uint_as_float(r.w & 0xffff0000u);
}
__device__ __forceinline__ void unpack_set(uint4 r, float* a) {
    a[0] = __uint_as_float(r.x << 16); a[1] = __uint_as_float(r.x & 0xffff0000u);
    a[2] = __uint_as_float(r.y << 16); a[3] = __uint_as_float(r.y & 0xffff0000u);
    a[4] = __uint_as_float(r.z << 16); a[5] = __uint_as_float(r.z & 0xffff0000u);
    a[6] = __uint_as_float(r.w << 16); a[7] = __uint_as_float(r.w & 0xffff0000u);
}
__device__ __forceinline__ void unpack_add2(uint2 r, float* a) {
    a[0] += __uint_as_float(r.x << 16); a[1] += __uint_as_float(r.x & 0xffff0000u);
    a[2] += __uint_as_float(r.y << 16); a[3] += __uint_as_float(r.y & 0xffff0000u);
}

// ---- dtype probe ----
__global__ void k_detect(const u16* __restrict__ p, int n, int* __restrict__ flag) {
    bool bad = false;
    for (int i = threadIdx.x; i < n; i += 256) {
        float v = bf2f(p[i]);
        if (!(v == v) || fabsf(v) > 1000.f) bad = true;
    }
    if (bad) atomicOr(flag, 1);
}

// ---- stage all weights as bf16 (multi-block, flat index -> segment) ----
__global__ void k_cvt_w(const void* W1, const void* b1, const void* W2, const void* b2,
                        const void* W3, const void* b3, const void* Wl, const void* bl,
                        const int* __restrict__ flag, u16* __restrict__ wbf) {
    int mode = *flag;
    int i = blockIdx.x * 256 + threadIdx.x;
    if (i >= 17216) return;
    const void* s; int base;
    if (i < 576)        { s = W1; base = 0; }
    else if (i < 640)   { s = b1; base = 576; }
    else if (i < 4736)  { s = W2; base = 640; }
    else if (i < 4800)  { s = b2; base = 4736; }
    else if (i < 8896)  { s = W3; base = 4800; }
    else if (i < 8960)  { s = b3; base = 8896; }
    else if (i < 17152) { s = Wl; base = 8960; }
    else                { s = bl; base = 17152; }
    int o = i - base;
    wbf[i] = mode ? f2bf(((const float*)s)[o]) : ((const u16*)s)[o];
}

// ==== atomic-free two-level radix CSR build ====
__global__ __launch_bounds__(256) void k_hist(const int* __restrict__ ei, int E, int nb,
                                              int chunk, int* __restrict__ cntmat) {
    __shared__ int h[NBM];
    int tid = threadIdx.x, k = blockIdx.x;
    for (int i = tid; i < nb; i += 256) h[i] = 0;
    __syncthreads();
    int e0 = k * chunk, e1 = e0 + chunk; if (e1 > E) e1 = E;
    for (int e = e0 + tid; e < e1; e += 256)
        atomicAdd(&h[ei[E + e] >> BSH], 1);
    __syncthreads();
    for (int b = tid; b < nb; b += 256) cntmat[b * NBLK + k] = h[b];
}

__global__ __launch_bounds__(1024) void k_scanmat(int* __restrict__ cntmat, int total) {
    __shared__ int ps[1024];
    int tid = threadIdx.x;
    int chunk = (total + 1023) >> 10;
    int i0 = tid * chunk, i1 = i0 + chunk; if (i1 > total) i1 = total;
    int sum = 0;
    for (int i = i0; i < i1; i++) sum += cntmat[i];
    ps[tid] = sum;
    __syncthreads();
    for (int off = 1; off < 1024; off <<= 1) {
        int t = (tid >= off) ? ps[tid - off] : 0;
        __syncthreads();
        ps[tid] += t;
        __syncthreads();
    }
    int run = ps[tid] - sum;
    for (int i = i0; i < i1; i++) { int c = cntmat[i]; cntmat[i] = run; run += c; }
}

__global__ __launch_bounds__(256) void k_scatter(const int* __restrict__ ei, int E, int nb,
                                                 int chunk, const int* __restrict__ offmat,
                                                 unsigned* __restrict__ staging) {
    __shared__ int cur[NBM];
    int tid = threadIdx.x, k = blockIdx.x;
    for (int b = tid; b < nb; b += 256) cur[b] = offmat[b * NBLK + k];
    __syncthreads();
    int e0 = k * chunk, e1 = e0 + chunk; if (e1 > E) e1 = E;
    for (int e = e0 + tid; e < e1; e += 256) {
        int s = ei[e];
        int d = ei[E + e];
        int b = d >> BSH;
        int p = atomicAdd(&cur[b], 1);
        staging[p] = (unsigned)s | ((unsigned)(d & ((1 << BSH) - 1)) << 18);
    }
}

__global__ __launch_bounds__(256) void k_p4(const unsigned* __restrict__ staging,
                                            const int* __restrict__ offmat, int nb, int N, int E,
                                            int* __restrict__ col, int* __restrict__ rowptr,
                                            float* __restrict__ dinv) {
    __shared__ int cnt[1 << BSH];
    __shared__ int cur[1 << BSH];
    __shared__ int ps[256];
    int b = blockIdx.x, tid = threadIdx.x;
    int s0 = offmat[b * NBLK];
    int s1 = (b == nb - 1) ? E : offmat[(b + 1) * NBLK];
    for (int i = tid; i < (1 << BSH); i += 256) cnt[i] = 0;
    __syncthreads();
    for (int i = s0 + tid; i < s1; i += 256)
        atomicAdd(&cnt[staging[i] >> 18], 1);
    __syncthreads();
    int base4 = tid * 4;
    int c0 = cnt[base4], c1 = cnt[base4 + 1], c2 = cnt[base4 + 2], c3 = cnt[base4 + 3];
    int tsum = c0 + c1 + c2 + c3;
    ps[tid] = tsum;
    __syncthreads();
    for (int off = 1; off < 256; off <<= 1) {
        int t = (tid >= off) ? ps[tid - off] : 0;
        __syncthreads();
        ps[tid] += t;
        __syncthreads();
    }
    int ex = ps[tid] - tsum;
    int o0 = s0 + ex, o1 = o0 + c0, o2 = o1 + c1, o3 = o2 + c2;
    cur[base4] = o0; cur[base4 + 1] = o1; cur[base4 + 2] = o2; cur[base4 + 3] = o3;
    int v = (b << BSH) + base4;
    if (v < N)     { rowptr[v] = o0;     dinv[v] = rsqrtf((float)(c0 + 1)); }
    if (v + 1 < N) { rowptr[v + 1] = o1; dinv[v + 1] = rsqrtf((float)(c1 + 1)); }
    if (v + 2 < N) { rowptr[v + 2] = o2; dinv[v + 2] = rsqrtf((float)(c2 + 1)); }
    if (v + 3 < N) { rowptr[v + 3] = o3; dinv[v + 3] = rsqrtf((float)(c3 + 1)); }
    if (b == nb - 1 && tid == 0) rowptr[N] = E;
    __syncthreads();
    for (int i = s0 + tid; i < s1; i += 256) {
        unsigned w = staging[i];
        int p = atomicAdd(&cur[w >> 18], 1);
        col[p] = (int)(w & 0x3FFFF);
    }
}

// ---- stage x: xd[v][16] = dinv[v] * x[v][0..8] (bf16, padded with 0) ----
__global__ void k_cvt_x(const void* __restrict__ x, const float* __restrict__ dinv,
                        const int* __restrict__ flag, int N, u16* __restrict__ xd) {
    int mode = *flag;
    int i = blockIdx.x * 256 + threadIdx.x;
    if (i >= N * 16) return;
    int v = i >> 4, f = i & 15;
    float val = 0.f;
    if (f < MOLD) {
        val = mode ? ((const float*)x)[v * MOLD + f]
                   : bf2f(((const u16*)x)[v * MOLD + f]);
        val *= dinv[v];
    }
    xd[i] = f2bf(val);
}

// ---- layer-1 gather in x-space (32B rows) + fused W1 multiply ----
// lane = eslot(0..15) x fq(0..3); gathers A = xd[v] + sum xd[u] (16 padded feats),
// then h1[v][lane] = relu(dinv[v] * sum_k A[k]*W1[k][lane] + b1[lane]).
__global__ __launch_bounds__(256, 4) void k_aggx(
        const u16* __restrict__ xd, const int* __restrict__ rowptr,
        const int* __restrict__ col, const float* __restrict__ dinv,
        const u16* __restrict__ W1, const u16* __restrict__ b1,
        int N, u16* __restrict__ h1) {
    int lane = threadIdx.x & 63;
    int eslot = lane >> 2, fq = lane & 3;
    float w1r[MOLD];
#pragma unroll
    for (int k = 0; k < MOLD; k++) w1r[k] = bf2f(W1[k * HID + lane]);
    float bias = bf2f(b1[lane]);
    bool sel0 = ((lane >> 2) & 1) != 0, sel1 = ((lane >> 3) & 1) != 0;
    int wid = (blockIdx.x * blockDim.x + threadIdx.x) >> 6;
    int nw = (gridDim.x * blockDim.x) >> 6;
    for (int v = wid; v < N; v += nw) {
        float acc[4];
        if (eslot == 0) {
            uint2 r = *(const uint2*)(xd + (size_t)v * 16 + fq * 4);
            acc[0] = __uint_as_float(r.x << 16); acc[1] = __uint_as_float(r.x & 0xffff0000u);
            acc[2] = __uint_as_float(r.y << 16); acc[3] = __uint_as_float(r.y & 0xffff0000u);
        } else {
#pragma unroll
            for (int j = 0; j < 4; j++) acc[j] = 0.f;
        }
        int e = rowptr[v + 1];
        for (int i = rowptr[v] + eslot; i < e; i += 16) {
            int u = col[i];
            uint2 r = *(const uint2*)(xd + (size_t)u * 16 + fq * 4);
            unpack_add2(r, acc);
        }
        // halving reduction over eslot bits (lane bits 2..5)
        float s0 = acc[0] + __shfl_xor(acc[0], 4);
        float s1 = acc[1] + __shfl_xor(acc[1], 4);
        float s2 = acc[2] + __shfl_xor(acc[2], 4);
        float s3 = acc[3] + __shfl_xor(acc[3], 4);
        float t0 = sel0 ? s2 : s0;
        float t1 = sel0 ? s3 : s1;
        t0 += __shfl_xor(t0, 8);
        t1 += __shfl_xor(t1, 8);
        float val = sel1 ? t1 : t0;
        val += __shfl_xor(val, 16);
        val += __shfl_xor(val, 32);
        // val on lane L holds feat f(L) = (L&3)*4 + ((L>>2)&1)*2 + ((L>>3)&1)
        // broadcast the 9 real feats and apply W1 column
        float accf = 0.f;
#pragma unroll
        for (int k = 0; k < MOLD; k++) {
            int Lk = (k >> 2) | ((k & 2) << 1) | ((k & 1) << 3);
            accf += __shfl(val, Lk) * w1r[k];
        }
        float h = fmaxf(dinv[v] * accf + bias, 0.f);
        h1[(size_t)v * HID + lane] = f2bf(h);
    }
}

// ---- gather core (64-feat rows): round-8 halving reduction ----
__device__ __forceinline__ float gather_node_one(const u16* __restrict__ y,
                                                 const int* __restrict__ rowptr,
                                                 const int* __restrict__ col,
                                                 float dv, float bias,
                                                 int v, int eslot, int fg) {
    float acc[8];
    const u16* yf = y + fg * 8;
    if (eslot == 0) {
        unpack_set(*(const uint4*)(yf + (size_t)v * HID), acc);
    } else {
#pragma unroll
        for (int j = 0; j < 8; j++) acc[j] = 0.f;
    }
    int e = rowptr[v + 1];
    for (int i = rowptr[v] + eslot; i < e; i += 8) {
        int u = col[i];
        uint4 r = *(const uint4*)(yf + (size_t)u * HID);
        unpack_add(r, acc);
    }
    bool e0 = (eslot & 1) != 0, e1 = (eslot & 2) != 0, e2 = (eslot & 4) != 0;
    float s[8];
#pragma unroll
    for (int j = 0; j < 8; j++) s[j] = acc[j] + __shfl_xor(acc[j], 8);
    float b4[4];
#pragma unroll
    for (int k = 0; k < 4; k++) b4[k] = e0 ? s[k + 4] : s[k];
#pragma unroll
    for (int k = 0; k < 4; k++) b4[k] += __shfl_xor(b4[k], 16);
    float c2[2];
    c2[0] = e1 ? b4[2] : b4[0];
    c2[1] = e1 ? b4[3] : b4[1];
    c2[0] += __shfl_xor(c2[0], 32);
    c2[1] += __shfl_xor(c2[1], 32);
    float val = e2 ? c2[1] : c2[0];
    return fmaxf(dv * val + bias, 0.f);
}

// ---- agg layer 2 (round-8 exact) ----
__global__ __launch_bounds__(256, 4) void k_agg(
        const u16* __restrict__ y, const int* __restrict__ rowptr,
        const int* __restrict__ col, const float* __restrict__ dinv,
        const u16* __restrict__ bseg, int N, u16* __restrict__ h) {
    int lane = threadIdx.x & 63;
    int eslot = lane >> 3, fg = lane & 7;
    int idx = fg * 8 + ((eslot & 1) << 2) + (eslot & 2) + ((eslot >> 2) & 1);
    float bias = bf2f(bseg[idx]);
    int wid = (blockIdx.x * blockDim.x + threadIdx.x) >> 6;
    int nw = (gridDim.x * blockDim.x) >> 6;
    for (int v = wid; v < N; v += nw) {
        float hv = gather_node_one(y, rowptr, col, dinv[v], bias, v, eslot, fg);
        h[(size_t)v * HID + idx] = f2bf(hv);
    }
}

// ---- agg layer 3 + fused pooling (round-8 exact) ----
__global__ __launch_bounds__(256, 4) void k_aggpool(
        const u16* __restrict__ y, const int* __restrict__ rowptr,
        const int* __restrict__ col, const float* __restrict__ dinv,
        const u16* __restrict__ bseg, const int* __restrict__ batch, int N,
        float* __restrict__ hsum, int* __restrict__ hmax, int* __restrict__ cnt) {
    int lane = threadIdx.x & 63;
    int eslot = lane >> 3, fg = lane & 7;
    int idx = fg * 8 + ((eslot & 1) << 2) + (eslot & 2) + ((eslot >> 2) & 1);
    float bias = bf2f(bseg[idx]);
    int wid = (blockIdx.x * blockDim.x + threadIdx.x) >> 6;
    int nw = (gridDim.x * blockDim.x) >> 6;
    int cpw = (N + nw - 1) / nw;
    int v0 = wid * cpw;
    int v1 = v0 + cpw; if (v1 > N) v1 = N;
    int gcur = -1, pcnt = 0;
    float psum = 0.f, pmax = 0.f;
    for (int v = v0; v < v1; ++v) {
        float hv = gather_node_one(y, rowptr, col, dinv[v], bias, v, eslot, fg);
        int g = batch[v];
        if (g != gcur) {
            if (gcur >= 0) {
                atomicAdd(&hsum[gcur * HID + idx], psum);
                atomicMax(&hmax[gcur * HID + idx], __float_as_int(pmax));
                if (lane == 0) atomicAdd(&cnt[gcur], pcnt);
            }
            psum = 0.f; pmax = 0.f; pcnt = 0;
            gcur = g;
        }
        pcnt++;
        psum += hv;
        pmax = fmaxf(pmax, hv);
    }
    if (gcur >= 0) {
        atomicAdd(&hsum[gcur * HID + idx], psum);
        atomicMax(&hmax[gcur * HID + idx], __float_as_int(pmax));
        if (lane == 0) atomicAdd(&cnt[gcur], pcnt);
    }
}

// ---- MFMA 64x64 dense: y = dinv * (h@W)  (round-8 exact) ----
__global__ __launch_bounds__(256, 4) void k_mm(
        const u16* __restrict__ h, const u16* __restrict__ W,
        const float* __restrict__ dinv, int N, u16* __restrict__ y) {
    int lane = threadIdx.x & 63;
    int q = lane >> 4, m = lane & 15;
    int wid = (blockIdx.x * blockDim.x + threadIdx.x) >> 6;
    int nw = (gridDim.x * blockDim.x) >> 6;
    short8 bfrag[4][2];
#pragma unroll
    for (int t = 0; t < 4; ++t)
#pragma unroll
        for (int kh = 0; kh < 2; ++kh) {
            short8 bv;
#pragma unroll
            for (int j = 0; j < 8; ++j)
                bv[j] = (short)W[(kh * 32 + q * 8 + j) * HID + t * 16 + m];
            bfrag[t][kh] = bv;
        }
    const float4v zero = {0.f, 0.f, 0.f, 0.f};
    int ntiles = (N + 15) >> 4;
    for (int tile = wid; tile < ntiles; tile += nw) {
        int base = tile * 16;
        int row = base + m;
        short8 a0 = {0, 0, 0, 0, 0, 0, 0, 0}, a1 = a0;
        if (row < N) {
            uint4 r0 = *(const uint4*)(h + (size_t)row * HID + q * 8);
            uint4 r1 = *(const uint4*)(h + (size_t)row * HID + 32 + q * 8);
            a0 = __builtin_bit_cast(short8, r0);
            a1 = __builtin_bit_cast(short8, r1);
        }
        float4v c[4];
#pragma unroll
        for (int t = 0; t < 4; ++t) c[t] = zero;
#pragma unroll
        for (int t = 0; t < 4; ++t) {
            c[t] = __builtin_amdgcn_mfma_f32_16x16x32_bf16(a0, bfrag[t][0], c[t], 0, 0, 0);
            c[t] = __builtin_amdgcn_mfma_f32_16x16x32_bf16(a1, bfrag[t][1], c[t], 0, 0, 0);
        }
#pragma unroll
        for (int r = 0; r < 4; ++r) {
            int node = base + q * 4 + r;
            if (node < N) {
                float dv = dinv[node];
#pragma unroll
                for (int t = 0; t < 4; ++t)
                    y[(size_t)node * HID + t * 16 + m] = f2bf(c[t][r] * dv);
            }
        }
    }
}

// ---- final linear ----
__global__ void k_final(const float* __restrict__ hsum, const int* __restrict__ hmaxi,
                        const int* __restrict__ cnt, const u16* __restrict__ wlseg,
                        const u16* __restrict__ blseg, const int* __restrict__ flag,
                        int G, void* __restrict__ out) {
    __shared__ float w[2 * HID * HID];
    int tid = threadIdx.x;
    for (int i = tid; i < 2 * HID * HID; i += blockDim.x) w[i] = bf2f(wlseg[i]);
    __syncthreads();
    int g = blockIdx.x * 4 + (tid >> 6);
    int f = tid & 63;
    if (g >= G) return;
    float inv = 1.f / fmaxf((float)cnt[g], 1.f);
    float acc = bf2f(blseg[f]);
#pragma unroll 8
    for (int k = 0; k < HID; k++) acc += (hsum[g * HID + k] * inv) * w[k * HID + f];
#pragma unroll 8
    for (int k = 0; k < HID; k++) acc += __int_as_float(hmaxi[g * HID + k]) * w[(HID + k) * HID + f];
    int mode = *flag;
    if (mode) ((float*)out)[g * HID + f] = acc;
    else      ((u16*)out)[g * HID + f] = f2bf(acc);
}

extern "C" void kernel_launch(void* const* d_in, const int* in_sizes, int n_in,
                              void* d_out, int out_size, void* d_ws, size_t ws_size,
                              hipStream_t stream) {
    const void* x  = d_in[0];
    const int*  ei = (const int*)d_in[1];
    const int*  batch = (const int*)d_in[3];

    const int NX = in_sizes[0];
    const int N  = NX / MOLD;
    const int E  = in_sizes[1] / 2;
    const int G  = out_size / HID;
    const int nb = (N + (1 << BSH) - 1) >> BSH;

    char* p = (char*)d_ws;
    auto alloc = [&](size_t bytes) -> char* {
        char* r = p;
        p += (bytes + 255) & ~(size_t)255;
        return r;
    };
    int*   flag    = (int*)alloc(256);
    int*   rowptr  = (int*)alloc((size_t)(N + 1) * 4);
    float* dinv    = (float*)alloc((size_t)N * 4);
    int*   cntmat  = (int*)alloc((size_t)nb * NBLK * 4);
    u16*   wbf     = (u16*)alloc((size_t)17216 * 2);
    int*   colb    = (int*)alloc((size_t)E * 4);
    // hbuf region reused sequentially: staging (CSR) -> xd (16-feat padded) -> y2 -> y3
    size_t hb = (size_t)N * HID * 2;           // 25.6 MB
    size_t sb = (size_t)E * 4;                 // 12.8 MB
    size_t xs = (size_t)N * 16 * 2;            // 6.4 MB
    size_t ub = hb; if (sb > ub) ub = sb; if (xs > ub) ub = xs;
    char* hbuf = alloc(ub);
    unsigned* staging = (unsigned*)hbuf;
    u16*      xd      = (u16*)hbuf;
    u16*      hbf     = (u16*)hbuf;
    u16*   ybf  = (u16*)alloc((size_t)N * HID * 2);
    float* hsum = (float*)alloc((size_t)G * HID * 4);
    int*   hmax = (int*)alloc((size_t)G * HID * 4);
    int*   cnt  = (int*)alloc((size_t)G * 4);

    hipMemsetAsync(flag, 0, 256, stream);
    hipMemsetAsync(hsum, 0, (size_t)G * HID * 4, stream);
    hipMemsetAsync(hmax, 0, (size_t)G * HID * 4, stream);
    hipMemsetAsync(cnt, 0, (size_t)G * 4, stream);

    k_detect<<<1, 256, 0, stream>>>((const u16*)x, 8192, flag);
    k_cvt_w<<<68, 256, 0, stream>>>(d_in[4], d_in[5], d_in[6], d_in[7],
                                    d_in[8], d_in[9], d_in[10], d_in[11], flag, wbf);

    int chunk = (E + NBLK - 1) / NBLK;
    k_hist<<<NBLK, 256, 0, stream>>>(ei, E, nb, chunk, cntmat);
    k_scanmat<<<1, 1024, 0, stream>>>(cntmat, nb * NBLK);
    k_scatter<<<NBLK, 256, 0, stream>>>(ei, E, nb, chunk, cntmat, staging);
    k_p4<<<nb, 256, 0, stream>>>(staging, cntmat, nb, N, E, colb, rowptr, dinv);

    // stage xd over dead staging; layer-1 gather in x-space fused with W1
    k_cvt_x<<<(N * 16 + 255) / 256, 256, 0, stream>>>(x, dinv, flag, N, xd);
    k_aggx<<<2048, 256, 0, stream>>>(xd, rowptr, colb, dinv, wbf + 0, wbf + 576,
                                     N, ybf);                                        // h1
    k_mm<<<1024, 256, 0, stream>>>(ybf, wbf + 640, dinv, N, hbf);                    // y2 (over xd, dead)
    k_agg<<<2048, 256, 0, stream>>>(hbf, rowptr, colb, dinv, wbf + 4736, N, ybf);    // h2
    k_mm<<<1024, 256, 0, stream>>>(ybf, wbf + 4800, dinv, N, hbf);                   // y3
    k_aggpool<<<2048, 256, 0, stream>>>(hbf, rowptr, colb, dinv, wbf + 8896, batch, N,
                                        hsum, hmax, cnt);

    k_final<<<(G + 3) / 4, 256, 0, stream>>>(hsum, hmax, cnt, wbf + 8960, wbf + 17152,
                                             flag, G, d_out);
}